// Round 1
// baseline (504.845 us; speedup 1.0000x reference)
//
#include <hip/hip_runtime.h>
#include <cstdint>
#include <cstddef>

#define DM 1024
#define NH 16
#define DKD 64
#define BB 4
#define SS 2048
#define MTOT (BB*SS)   // 8192 rows

typedef float  f32x4  __attribute__((ext_vector_type(4)));
typedef __bf16 bf16x8 __attribute__((ext_vector_type(8)));
typedef __bf16 bf16x4v __attribute__((ext_vector_type(4)));
typedef __bf16 bf16x2v __attribute__((ext_vector_type(2)));
using as3v = __attribute__((address_space(3))) void;
using as1v = __attribute__((address_space(1))) void;

__device__ __forceinline__ void gl2lds16(const void* g, void* l) {
  __builtin_amdgcn_global_load_lds((as1v*)g, (as3v*)l, 16, 0, 0);
}

// ---------------- cast fp32 -> bf16 (vectorized x4) ----------------
__global__ void cast_f32_bf16_k(const float* __restrict__ in, __bf16* __restrict__ out, int n4) {
  int i = blockIdx.x * blockDim.x + threadIdx.x;
  if (i >= n4) return;
  float4 f = ((const float4*)in)[i];
  bf16x4v o;
  o[0] = (__bf16)f.x; o[1] = (__bf16)f.y; o[2] = (__bf16)f.z; o[3] = (__bf16)f.w;
  ((bf16x4v*)out)[i] = o;
}

// ---------------- GEMM: C[M,N] = A[M,K] * B[N,K]^T  (bf16 in, CT out) ----------------
// 128x128 tile, BK=32, 4 waves in 2x2, each wave 64x64 via 4x4 16x16x32 MFMAs.
template <typename CT>
__global__ __launch_bounds__(256) void gemm_bt_k(const __bf16* __restrict__ A,
                                                 const __bf16* __restrict__ B,
                                                 CT* __restrict__ C,
                                                 int M, int N, int K) {
  __shared__ __bf16 As[128 * 32];
  __shared__ __bf16 Bs[128 * 32];
  const int tid  = threadIdx.x;
  const int lane = tid & 63;
  const int wid  = tid >> 6;
  const int lrow = lane & 15;
  const int quad = lane >> 4;
  const int m0 = blockIdx.y * 128;
  const int n0 = blockIdx.x * 128;
  const int wm = (wid & 1) * 64;
  const int wn = (wid >> 1) * 64;
  const int srow = wid * 32 + (lane >> 2);   // staging row for this lane (j=0)
  const int scol = (lane & 3) * 8;           // staging k-offset (elements)

  f32x4 acc[4][4] = {};

  for (int k0 = 0; k0 < K; k0 += 32) {
    __syncthreads();
    // global -> LDS, 16B/lane, wave-uniform LDS base + lane*16
    gl2lds16(A + (size_t)(m0 + srow)      * K + k0 + scol, As + (wid * 32)      * 32);
    gl2lds16(A + (size_t)(m0 + srow + 16) * K + k0 + scol, As + (wid * 32 + 16) * 32);
    gl2lds16(B + (size_t)(n0 + srow)      * K + k0 + scol, Bs + (wid * 32)      * 32);
    gl2lds16(B + (size_t)(n0 + srow + 16) * K + k0 + scol, Bs + (wid * 32 + 16) * 32);
    __syncthreads();

    bf16x8 af[4], bfr[4];
#pragma unroll
    for (int i = 0; i < 4; ++i)
      af[i] = *(const bf16x8*)(As + (wm + i * 16 + lrow) * 32 + quad * 8);
#pragma unroll
    for (int i = 0; i < 4; ++i)
      bfr[i] = *(const bf16x8*)(Bs + (wn + i * 16 + lrow) * 32 + quad * 8);
#pragma unroll
    for (int mi = 0; mi < 4; ++mi)
#pragma unroll
      for (int ni = 0; ni < 4; ++ni)
        acc[mi][ni] = __builtin_amdgcn_mfma_f32_16x16x32_bf16(af[mi], bfr[ni], acc[mi][ni], 0, 0, 0);
  }

#pragma unroll
  for (int mi = 0; mi < 4; ++mi)
#pragma unroll
    for (int ni = 0; ni < 4; ++ni)
#pragma unroll
      for (int r = 0; r < 4; ++r) {
        int row = m0 + wm + mi * 16 + quad * 4 + r;
        int col = n0 + wn + ni * 16 + lrow;
        C[(size_t)row * N + col] = (CT)acc[mi][ni][r];
      }
}

// ---------------- RoPE (interleaved pairs), in-place on Q and K ----------------
__global__ void rope_k(__bf16* __restrict__ Q, __bf16* __restrict__ Kt,
                       const int* __restrict__ pos) {
  int p = blockIdx.x * blockDim.x + threadIdx.x;  // 0 .. MTOT*512-1
  int row = p >> 9;        // / 512 pairs per row
  int wi  = p & 511;
  int h = wi >> 5;         // 32 pairs per head
  int i = wi & 31;
  int s = row & (SS - 1);
  float ps  = (float)pos[s];
  // inv_freq = 10000^(-2i/64) = exp(-i * 2*ln(1e4)/64)
  float inv = __expf(-0.28782313663f * (float)i);
  float ang = ps * inv;
  float sn, cs;
  sincosf(ang, &sn, &cs);
  size_t base = (size_t)row * DM + h * DKD + 2 * i;
  bf16x2v q = *(bf16x2v*)(Q + base);
  float q1 = (float)q[0], q2 = (float)q[1];
  bf16x2v qo; qo[0] = (__bf16)(q1 * cs - q2 * sn); qo[1] = (__bf16)(q1 * sn + q2 * cs);
  *(bf16x2v*)(Q + base) = qo;
  bf16x2v k = *(bf16x2v*)(Kt + base);
  float k1 = (float)k[0], k2 = (float)k[1];
  bf16x2v ko; ko[0] = (__bf16)(k1 * cs - k2 * sn); ko[1] = (__bf16)(k1 * sn + k2 * cs);
  *(bf16x2v*)(Kt + base) = ko;
}

// ---------------- Flash attention, causal, one block per (b,h,64-row q-tile) ----------------
// 4 waves; wave w owns q-rows [q0+16w, q0+16w+16). Online softmax wave-local.
__global__ __launch_bounds__(256) void attn_k(const __bf16* __restrict__ Q,
                                              const __bf16* __restrict__ K,
                                              const __bf16* __restrict__ V,
                                              __bf16* __restrict__ O) {
  __shared__ __bf16 Ks[64 * 72];        // [key][dk], stride 72 (bank-conflict pad, 16B-aligned)
  __shared__ __bf16 Vt[64 * 68];        // [dk][key], stride 68 (8B-aligned, b64 frag reads)
  __shared__ __bf16 Pt[4][16 * 72];     // per-wave P tile [qrow][key]
  const int tid  = threadIdx.x;
  const int lane = tid & 63;
  const int wid  = tid >> 6;
  const int lrow = lane & 15;
  const int quad = lane >> 4;
  const int bh = blockIdx.y;
  const int b  = bh >> 4;
  const int h  = bh & 15;
  const int q0 = blockIdx.x * 64;
  const size_t bbase = (size_t)b * SS * DM;
  const int hoff = h * DKD;

  // Q A-fragments for the wave's 16 rows (2 k-steps over dk)
  bf16x8 qf0, qf1;
  {
    const __bf16* qp = Q + bbase + (size_t)(q0 + wid * 16 + lrow) * DM + hoff + quad * 8;
    qf0 = *(const bf16x8*)(qp);
    qf1 = *(const bf16x8*)(qp + 32);
  }
  f32x4 Oa[4] = {};
  float mr[4] = {-1e30f, -1e30f, -1e30f, -1e30f};
  float lsum[4] = {0.f, 0.f, 0.f, 0.f};

  const int nkt = blockIdx.x + 1;  // causal: k-tiles 0..blockIdx.x
  for (int kt = 0; kt < nkt; ++kt) {
    __syncthreads();
    // stage K [key][dk] and V transposed [dk][key]
    for (int c = tid; c < 512; c += 256) {
      int krow = c >> 3;
      int ck = (c & 7) * 8;
      size_t goff = bbase + (size_t)(kt * 64 + krow) * DM + hoff + ck;
      bf16x8 kk = *(const bf16x8*)(K + goff);
      *(bf16x8*)(&Ks[krow * 72 + ck]) = kk;
      bf16x8 vv = *(const bf16x8*)(V + goff);
#pragma unroll
      for (int j = 0; j < 8; ++j) Vt[(ck + j) * 68 + krow] = vv[j];
    }
    __syncthreads();

    // S = Q * K^T  (16 q-rows x 64 keys per wave)
    f32x4 sa[4] = {};
#pragma unroll
    for (int ni = 0; ni < 4; ++ni) {
      bf16x8 bfr = *(const bf16x8*)(&Ks[(ni * 16 + lrow) * 72 + quad * 8]);
      sa[ni] = __builtin_amdgcn_mfma_f32_16x16x32_bf16(qf0, bfr, sa[ni], 0, 0, 0);
    }
#pragma unroll
    for (int ni = 0; ni < 4; ++ni) {
      bf16x8 bfr = *(const bf16x8*)(&Ks[(ni * 16 + lrow) * 72 + 32 + quad * 8]);
      sa[ni] = __builtin_amdgcn_mfma_f32_16x16x32_bf16(qf1, bfr, sa[ni], 0, 0, 0);
    }

    // online softmax per row (rows quad*4+r; stats replicated over the 16 lanes of a quad-group)
#pragma unroll
    for (int r = 0; r < 4; ++r) {
      const int grow = q0 + wid * 16 + quad * 4 + r;
      float sv[4];
      float mx = -1e30f;
#pragma unroll
      for (int ni = 0; ni < 4; ++ni) {
        int gcol = kt * 64 + ni * 16 + lrow;
        float s = sa[ni][r] * 0.125f;          // 1/sqrt(64)
        if (gcol > grow) s = -1e30f;           // causal mask
        sv[ni] = s;
        mx = fmaxf(mx, s);
      }
#pragma unroll
      for (int off = 1; off < 16; off <<= 1) mx = fmaxf(mx, __shfl_xor(mx, off, 64));
      float mnew  = fmaxf(mr[r], mx);
      float alpha = __expf(mr[r] - mnew);
      mr[r] = mnew;
      float psum = 0.f;
#pragma unroll
      for (int ni = 0; ni < 4; ++ni) {
        float pv = __expf(sv[ni] - mnew);
        psum += pv;
        Pt[wid][(quad * 4 + r) * 72 + ni * 16 + lrow] = (__bf16)pv;
      }
#pragma unroll
      for (int off = 1; off < 16; off <<= 1) psum += __shfl_xor(psum, off, 64);
      lsum[r] = lsum[r] * alpha + psum;
#pragma unroll
      for (int ni = 0; ni < 4; ++ni) Oa[ni][r] *= alpha;
    }

    // O += P * V   (A = P from per-wave LDS, B = V^T tile)
#pragma unroll
    for (int t = 0; t < 2; ++t) {
      bf16x8 pf = *(const bf16x8*)(&Pt[wid][lrow * 72 + t * 32 + quad * 8]);
#pragma unroll
      for (int ni = 0; ni < 4; ++ni) {
        const __bf16* vp = &Vt[(ni * 16 + lrow) * 68 + t * 32 + quad * 8];
        bf16x4v lo = *(const bf16x4v*)(vp);
        bf16x4v hi = *(const bf16x4v*)(vp + 4);
        bf16x8 vf;
#pragma unroll
        for (int j = 0; j < 4; ++j) { vf[j] = lo[j]; vf[4 + j] = hi[j]; }
        Oa[ni] = __builtin_amdgcn_mfma_f32_16x16x32_bf16(pf, vf, Oa[ni], 0, 0, 0);
      }
    }
  }

  // normalize + write context [b*s][h*64+dk]
#pragma unroll
  for (int ni = 0; ni < 4; ++ni)
#pragma unroll
    for (int r = 0; r < 4; ++r) {
      int grow = q0 + wid * 16 + quad * 4 + r;
      float val = Oa[ni][r] / lsum[r];
      O[bbase + (size_t)grow * DM + hoff + ni * 16 + lrow] = (__bf16)val;
    }
}

// ---------------- launch ----------------
extern "C" void kernel_launch(void* const* d_in, const int* in_sizes, int n_in,
                              void* d_out, int out_size, void* d_ws, size_t ws_size,
                              hipStream_t stream) {
  (void)in_sizes; (void)n_in; (void)out_size; (void)ws_size;
  const float* x  = (const float*)d_in[0];
  const int*   pos = (const int*)d_in[1];
  const float* WQ = (const float*)d_in[2];
  const float* WK = (const float*)d_in[3];
  const float* WV = (const float*)d_in[4];
  const float* WO = (const float*)d_in[5];
  float* out = (float*)d_out;

  char* w = (char*)d_ws;
  const size_t MB = 1024 * 1024;
  __bf16* xb  = (__bf16*)(w);             // 16 MB
  __bf16* wqb = (__bf16*)(w + 16 * MB);   // 2 MB each
  __bf16* wkb = (__bf16*)(w + 18 * MB);
  __bf16* wvb = (__bf16*)(w + 20 * MB);
  __bf16* wob = (__bf16*)(w + 22 * MB);
  __bf16* Qb  = (__bf16*)(w + 24 * MB);   // 16 MB each
  __bf16* Kb  = (__bf16*)(w + 40 * MB);
  __bf16* Vb  = (__bf16*)(w + 56 * MB);
  __bf16* Cb  = (__bf16*)(w + 72 * MB);   // context, ends at 88 MB

  // casts
  cast_f32_bf16_k<<<(MTOT * DM / 4 + 255) / 256, 256, 0, stream>>>(x, xb, MTOT * DM / 4);
  cast_f32_bf16_k<<<(DM * DM / 4 + 255) / 256, 256, 0, stream>>>(WQ, wqb, DM * DM / 4);
  cast_f32_bf16_k<<<(DM * DM / 4 + 255) / 256, 256, 0, stream>>>(WK, wkb, DM * DM / 4);
  cast_f32_bf16_k<<<(DM * DM / 4 + 255) / 256, 256, 0, stream>>>(WV, wvb, DM * DM / 4);
  cast_f32_bf16_k<<<(DM * DM / 4 + 255) / 256, 256, 0, stream>>>(WO, wob, DM * DM / 4);

  // Q/K/V projections: [8192,1024] x [1024,1024]^T
  dim3 gg(DM / 128, MTOT / 128);
  gemm_bt_k<__bf16><<<gg, 256, 0, stream>>>(xb, wqb, Qb, MTOT, DM, DM);
  gemm_bt_k<__bf16><<<gg, 256, 0, stream>>>(xb, wkb, Kb, MTOT, DM, DM);
  gemm_bt_k<__bf16><<<gg, 256, 0, stream>>>(xb, wvb, Vb, MTOT, DM, DM);

  // RoPE on Q,K
  rope_k<<<(MTOT * 512) / 256, 256, 0, stream>>>(Qb, Kb, pos);

  // attention -> context
  attn_k<<<dim3(SS / 64, BB * NH), 256, 0, stream>>>(Qb, Kb, Vb, Cb);

  // output projection (fp32 out)
  gemm_bt_k<float><<<gg, 256, 0, stream>>>(Cb, wob, out, MTOT, DM, DM);
}

// Round 3
// 339.672 us; speedup vs baseline: 1.4863x; 1.4863x over previous
//
#include <hip/hip_runtime.h>
#include <cstdint>
#include <cstddef>

#define DM 1024
#define NH 16
#define DKD 64
#define BB 4
#define SS 2048
#define MTOT (BB*SS)   // 8192 rows

typedef float  f32x4  __attribute__((ext_vector_type(4)));
typedef __bf16 bf16x8 __attribute__((ext_vector_type(8)));
typedef __bf16 bf16x4v __attribute__((ext_vector_type(4)));
typedef __bf16 bf16x2v __attribute__((ext_vector_type(2)));
using as3v = __attribute__((address_space(3))) void;
using as1v = __attribute__((address_space(1))) void;

__device__ __forceinline__ void gl2lds16(const void* g, void* l) {
  __builtin_amdgcn_global_load_lds((as1v*)g, (as3v*)l, 16, 0, 0);
}

__device__ __forceinline__ float fast_exp2(float x) {
#if __has_builtin(__builtin_amdgcn_exp2f)
  return __builtin_amdgcn_exp2f(x);
#else
  return __expf(x * 0.6931471805599453f);
#endif
}

// ---------------- cast fp32 -> bf16 (vectorized x4) ----------------
__global__ void cast_f32_bf16_k(const float* __restrict__ in, __bf16* __restrict__ out, int n4) {
  int i = blockIdx.x * blockDim.x + threadIdx.x;
  if (i >= n4) return;
  float4 f = ((const float4*)in)[i];
  bf16x4v o;
  o[0] = (__bf16)f.x; o[1] = (__bf16)f.y; o[2] = (__bf16)f.z; o[3] = (__bf16)f.w;
  ((bf16x4v*)out)[i] = o;
}

// ---------------- GEMM: C[M,N] = A[M,K] * B[N,K]^T  (token-major C) ----------------
template <typename CT>
__global__ __launch_bounds__(256) void gemm_bt_k(const __bf16* __restrict__ A,
                                                 const __bf16* __restrict__ B,
                                                 CT* __restrict__ C,
                                                 int M, int N, int K) {
  __shared__ __bf16 As[128 * 32];
  __shared__ __bf16 Bs[128 * 32];
  const int tid  = threadIdx.x;
  const int lane = tid & 63;
  const int wid  = tid >> 6;
  const int lrow = lane & 15;
  const int quad = lane >> 4;
  const int m0 = blockIdx.y * 128;
  const int n0 = blockIdx.x * 128;
  const int wm = (wid & 1) * 64;
  const int wn = (wid >> 1) * 64;
  const int srow = wid * 32 + (lane >> 2);
  const int scol = (lane & 3) * 8;

  f32x4 acc[4][4] = {};

  for (int k0 = 0; k0 < K; k0 += 32) {
    __syncthreads();
    gl2lds16(A + (size_t)(m0 + srow)      * K + k0 + scol, As + (wid * 32)      * 32);
    gl2lds16(A + (size_t)(m0 + srow + 16) * K + k0 + scol, As + (wid * 32 + 16) * 32);
    gl2lds16(B + (size_t)(n0 + srow)      * K + k0 + scol, Bs + (wid * 32)      * 32);
    gl2lds16(B + (size_t)(n0 + srow + 16) * K + k0 + scol, Bs + (wid * 32 + 16) * 32);
    __syncthreads();

    bf16x8 af[4], bfr[4];
#pragma unroll
    for (int i = 0; i < 4; ++i)
      af[i] = *(const bf16x8*)(As + (wm + i * 16 + lrow) * 32 + quad * 8);
#pragma unroll
    for (int i = 0; i < 4; ++i)
      bfr[i] = *(const bf16x8*)(Bs + (wn + i * 16 + lrow) * 32 + quad * 8);
#pragma unroll
    for (int mi = 0; mi < 4; ++mi)
#pragma unroll
      for (int ni = 0; ni < 4; ++ni)
        acc[mi][ni] = __builtin_amdgcn_mfma_f32_16x16x32_bf16(af[mi], bfr[ni], acc[mi][ni], 0, 0, 0);
  }

#pragma unroll
  for (int mi = 0; mi < 4; ++mi)
#pragma unroll
    for (int ni = 0; ni < 4; ++ni)
#pragma unroll
      for (int r = 0; r < 4; ++r) {
        int row = m0 + wm + mi * 16 + quad * 4 + r;
        int col = n0 + wn + ni * 16 + lrow;
        C[(size_t)row * N + col] = (CT)acc[mi][ni][r];
      }
}

// ---------------- fused QKV GEMM, head-major output [bh][s][64] ----------------
__global__ __launch_bounds__(256) void gemm_qkv_k(const __bf16* __restrict__ A,
                                                  const __bf16* __restrict__ Bq,
                                                  const __bf16* __restrict__ Bk,
                                                  const __bf16* __restrict__ Bv,
                                                  __bf16* __restrict__ Cq,
                                                  __bf16* __restrict__ Ck,
                                                  __bf16* __restrict__ Cv) {
  __shared__ __bf16 As[128 * 32];
  __shared__ __bf16 Bs[128 * 32];
  const int sel = blockIdx.x >> 3;
  const __bf16* B = sel == 0 ? Bq : sel == 1 ? Bk : Bv;
  __bf16* C = sel == 0 ? Cq : sel == 1 ? Ck : Cv;
  const int n0 = (blockIdx.x & 7) * 128;
  const int m0 = blockIdx.y * 128;
  const int K = DM;
  const int tid  = threadIdx.x;
  const int lane = tid & 63;
  const int wid  = tid >> 6;
  const int lrow = lane & 15;
  const int quad = lane >> 4;
  const int wm = (wid & 1) * 64;
  const int wn = (wid >> 1) * 64;
  const int srow = wid * 32 + (lane >> 2);
  const int scol = (lane & 3) * 8;

  f32x4 acc[4][4] = {};

  for (int k0 = 0; k0 < K; k0 += 32) {
    __syncthreads();
    gl2lds16(A + (size_t)(m0 + srow)      * K + k0 + scol, As + (wid * 32)      * 32);
    gl2lds16(A + (size_t)(m0 + srow + 16) * K + k0 + scol, As + (wid * 32 + 16) * 32);
    gl2lds16(B + (size_t)(n0 + srow)      * K + k0 + scol, Bs + (wid * 32)      * 32);
    gl2lds16(B + (size_t)(n0 + srow + 16) * K + k0 + scol, Bs + (wid * 32 + 16) * 32);
    __syncthreads();

    bf16x8 af[4], bfr[4];
#pragma unroll
    for (int i = 0; i < 4; ++i)
      af[i] = *(const bf16x8*)(As + (wm + i * 16 + lrow) * 32 + quad * 8);
#pragma unroll
    for (int i = 0; i < 4; ++i)
      bfr[i] = *(const bf16x8*)(Bs + (wn + i * 16 + lrow) * 32 + quad * 8);
#pragma unroll
    for (int mi = 0; mi < 4; ++mi)
#pragma unroll
      for (int ni = 0; ni < 4; ++ni)
        acc[mi][ni] = __builtin_amdgcn_mfma_f32_16x16x32_bf16(af[mi], bfr[ni], acc[mi][ni], 0, 0, 0);
  }

  const int hbase = (n0 + wn) >> 6;   // head index for this wave's 64-col block
#pragma unroll
  for (int mi = 0; mi < 4; ++mi)
#pragma unroll
    for (int ni = 0; ni < 4; ++ni)
#pragma unroll
      for (int r = 0; r < 4; ++r) {
        int row = m0 + wm + mi * 16 + quad * 4 + r;
        int b = row >> 11;
        int s = row & (SS - 1);
        int d = ni * 16 + lrow;
        C[((size_t)(b * NH + hbase)) * (SS * DKD) + (size_t)s * DKD + d] = (__bf16)acc[mi][ni][r];
      }
}

// ---------------- RoPE on head-major Q,K in-place ----------------
__global__ void rope2_k(__bf16* __restrict__ Qh, __bf16* __restrict__ Kh,
                        const int* __restrict__ pos) {
  int p = blockIdx.x * blockDim.x + threadIdx.x;  // 64*2048*32
  int i = p & 31;
  int s = (p >> 5) & (SS - 1);
  int bh = p >> 16;
  float ps  = (float)pos[s];
  float inv = __expf(-0.28782313663f * (float)i);
  float ang = ps * inv;
  float sn, cs;
  sincosf(ang, &sn, &cs);
  size_t base = (size_t)bh * (SS * DKD) + (size_t)s * DKD + 2 * i;
  bf16x2v q = *(bf16x2v*)(Qh + base);
  float q1 = (float)q[0], q2 = (float)q[1];
  bf16x2v qo; qo[0] = (__bf16)(q1 * cs - q2 * sn); qo[1] = (__bf16)(q1 * sn + q2 * cs);
  *(bf16x2v*)(Qh + base) = qo;
  bf16x2v k = *(bf16x2v*)(Kh + base);
  float k1 = (float)k[0], k2 = (float)k[1];
  bf16x2v ko; ko[0] = (__bf16)(k1 * cs - k2 * sn); ko[1] = (__bf16)(k1 * sn + k2 * cs);
  *(bf16x2v*)(Kh + base) = ko;
}

// ---------------- V transpose: Vh [bh][s][64] -> VT [bh][64][s] ----------------
__global__ __launch_bounds__(256) void vtrans_k(const __bf16* __restrict__ Vh,
                                                __bf16* __restrict__ VT) {
  __shared__ __bf16 T[64][72];
  const int bh = blockIdx.y;
  const int s0 = blockIdx.x * 64;
  const size_t base = (size_t)bh * (SS * DKD);
#pragma unroll
  for (int it = 0; it < 2; ++it) {
    int idx = it * 256 + threadIdx.x;
    int sl = idx >> 3;
    int c  = idx & 7;
    bf16x8 v = *(const bf16x8*)(Vh + base + (size_t)(s0 + sl) * DKD + c * 8);
#pragma unroll
    for (int j = 0; j < 8; ++j) T[c * 8 + j][sl] = v[j];
  }
  __syncthreads();
#pragma unroll
  for (int it = 0; it < 2; ++it) {
    int idx = it * 256 + threadIdx.x;
    int d  = idx >> 3;
    int c2 = idx & 7;
    bf16x8 o = *(const bf16x8*)(&T[d][c2 * 8]);
    *(bf16x8*)(VT + base + (size_t)d * SS + s0 + c2 * 8) = o;
  }
}

// ---------------- attention v2: S^T orientation, static-shift softmax ----------------
// block = 4 waves x 16 q-rows = 64 q; K-tile = 128 keys; causal.
__global__ __launch_bounds__(256) void attn2_k(const __bf16* __restrict__ Qh,
                                               const __bf16* __restrict__ Kh,
                                               const __bf16* __restrict__ VT,
                                               __bf16* __restrict__ O) {
  __shared__ __bf16 Ks[128 * 64];      // swizzled [key][chunk8]
  __shared__ __bf16 Vt[64 * 128];      // swizzled [dk][chunk8 of 16]
  __shared__ __bf16 Pt[4][16 * 136];   // per-wave P [q][key], stride 136
  const int tid  = threadIdx.x;
  const int lane = tid & 63;
  const int wid  = tid >> 6;
  const int lrow = lane & 15;
  const int quad = lane >> 4;
  const int bh = blockIdx.y;
  const int b  = bh >> 4;
  const int h  = bh & 15;
  const int qi = (int)gridDim.x - 1 - (int)blockIdx.x;   // heavy tiles first
  const int q0 = qi * 64;
  const size_t hb = (size_t)bh * (SS * DKD);
  const int qg = q0 + wid * 16 + lrow;  // this lane's q-row (col of S^T)

  bf16x8 qf0, qf1;
  {
    const __bf16* qp = Qh + hb + (size_t)qg * DKD + quad * 8;
    qf0 = *(const bf16x8*)qp;
    qf1 = *(const bf16x8*)(qp + 32);
  }
  f32x4 Oa[4] = {};
  float l = 0.f;
  const int nkt = (q0 + 64 + 127) >> 7;

  const int skr = lane >> 3;   // K staging: row-local 0..7
  const int skc = lane & 7;    //            chunk 0..7
  const int svd = lane >> 4;   // V staging: dk-local 0..3
  const int svc = lane & 15;   //            chunk 0..15

  for (int kt = 0; kt < nkt; ++kt) {
    __syncthreads();
#pragma unroll
    for (int ii = 0; ii < 4; ++ii) {
      int i = wid * 4 + ii;
      int key = i * 8 + skr;
      int gc = skc ^ (key & 7);
      gl2lds16(Kh + hb + (size_t)(kt * 128 + key) * DKD + gc * 8, Ks + i * 512);
      int dk = i * 4 + svd;
      int gc2 = (svc & 8) | ((svc ^ dk) & 7);
      // each call writes 512 elements (64 lanes x 16B); dk-rows i*4..i*4+3 => base i*512
      gl2lds16(VT + hb + (size_t)dk * SS + kt * 128 + gc2 * 8, Vt + i * 512);
    }
    __syncthreads();

    // S^T = K * Q^T : A = K-frag (m=key), B = Q-frag (n=q)
    f32x4 sa[8];
#pragma unroll
    for (int mi = 0; mi < 8; ++mi) sa[mi] = (f32x4){0.f, 0.f, 0.f, 0.f};
#pragma unroll
    for (int t = 0; t < 2; ++t) {
      bf16x8 qf = t ? qf1 : qf0;
#pragma unroll
      for (int mi = 0; mi < 8; ++mi) {
        bf16x8 kf = *(const bf16x8*)(Ks + (mi * 16 + lrow) * 64 + (((t * 4 + quad) ^ (lrow & 7)) * 8));
        sa[mi] = __builtin_amdgcn_mfma_f32_16x16x32_bf16(kf, qf, sa[mi], 0, 0, 0);
      }
    }

    // softmax: p = exp2(s * (1/8)*log2e - 8); all 32 scores/lane share q-row qg
    if (kt == nkt - 1) {
#pragma unroll
      for (int mi = 0; mi < 8; ++mi) {
        bf16x4v pk;
#pragma unroll
        for (int r = 0; r < 4; ++r) {
          int key = kt * 128 + mi * 16 + quad * 4 + r;
          float p = fast_exp2(sa[mi][r] * 0.18033688f - 8.0f);
          p = (key <= qg) ? p : 0.f;
          l += p;
          pk[r] = (__bf16)p;
        }
        *(bf16x4v*)(&Pt[wid][lrow * 136 + mi * 16 + quad * 4]) = pk;
      }
    } else {
#pragma unroll
      for (int mi = 0; mi < 8; ++mi) {
        bf16x4v pk;
#pragma unroll
        for (int r = 0; r < 4; ++r) {
          float p = fast_exp2(sa[mi][r] * 0.18033688f - 8.0f);
          l += p;
          pk[r] = (__bf16)p;
        }
        *(bf16x4v*)(&Pt[wid][lrow * 136 + mi * 16 + quad * 4]) = pk;
      }
    }

    // O += P * V : A = P-frag (b128 from per-wave Pt), B = V^T-frag (swizzled Vt)
#pragma unroll
    for (int kc = 0; kc < 4; ++kc) {
      bf16x8 pf = *(const bf16x8*)(&Pt[wid][lrow * 136 + kc * 32 + quad * 8]);
#pragma unroll
      for (int ni = 0; ni < 4; ++ni) {
        int c = kc * 4 + quad;
        int cp = (c & 8) | ((c ^ (lrow & 7)) & 7);
        bf16x8 vf = *(const bf16x8*)(Vt + (ni * 16 + lrow) * 128 + cp * 8);
        Oa[ni] = __builtin_amdgcn_mfma_f32_16x16x32_bf16(pf, vf, Oa[ni], 0, 0, 0);
      }
    }
  }

  // deferred l reduction: sum across the 4 quads (once per kernel)
  l += __shfl_xor(l, 16, 64);
  l += __shfl_xor(l, 32, 64);

  // normalize + write context token-major [b][s][h*64+d]
#pragma unroll
  for (int r = 0; r < 4; ++r) {
    float li = __shfl(l, quad * 4 + r, 64);   // l for q-row quad*4+r
    float inv = 1.0f / li;
    int row = q0 + wid * 16 + quad * 4 + r;
#pragma unroll
    for (int ni = 0; ni < 4; ++ni)
      O[(size_t)b * SS * DM + (size_t)row * DM + h * DKD + ni * 16 + lrow] =
          (__bf16)(Oa[ni][r] * inv);
  }
}

// ---------------- launch ----------------
extern "C" void kernel_launch(void* const* d_in, const int* in_sizes, int n_in,
                              void* d_out, int out_size, void* d_ws, size_t ws_size,
                              hipStream_t stream) {
  (void)in_sizes; (void)n_in; (void)out_size; (void)ws_size;
  const float* x  = (const float*)d_in[0];
  const int*   pos = (const int*)d_in[1];
  const float* WQ = (const float*)d_in[2];
  const float* WK = (const float*)d_in[3];
  const float* WV = (const float*)d_in[4];
  const float* WO = (const float*)d_in[5];
  float* out = (float*)d_out;

  char* w = (char*)d_ws;
  const size_t MB = 1024 * 1024;
  __bf16* xb  = (__bf16*)(w);             // 16 MB
  __bf16* wqb = (__bf16*)(w + 16 * MB);
  __bf16* wkb = (__bf16*)(w + 18 * MB);
  __bf16* wvb = (__bf16*)(w + 20 * MB);
  __bf16* wob = (__bf16*)(w + 22 * MB);
  __bf16* Qh  = (__bf16*)(w + 24 * MB);   // head-major [bh][s][64]
  __bf16* Kh  = (__bf16*)(w + 40 * MB);
  __bf16* Vh  = (__bf16*)(w + 56 * MB);   // head-major V (dead after vtrans)
  __bf16* VT  = (__bf16*)(w + 72 * MB);   // [bh][64][s]
  __bf16* Cb  = (__bf16*)(w + 56 * MB);   // context token-major, aliases Vh

  cast_f32_bf16_k<<<(MTOT * DM / 4 + 255) / 256, 256, 0, stream>>>(x, xb, MTOT * DM / 4);
  cast_f32_bf16_k<<<(DM * DM / 4 + 255) / 256, 256, 0, stream>>>(WQ, wqb, DM * DM / 4);
  cast_f32_bf16_k<<<(DM * DM / 4 + 255) / 256, 256, 0, stream>>>(WK, wkb, DM * DM / 4);
  cast_f32_bf16_k<<<(DM * DM / 4 + 255) / 256, 256, 0, stream>>>(WV, wvb, DM * DM / 4);
  cast_f32_bf16_k<<<(DM * DM / 4 + 255) / 256, 256, 0, stream>>>(WO, wob, DM * DM / 4);

  // fused QKV projection, head-major outputs
  gemm_qkv_k<<<dim3(24, MTOT / 128), 256, 0, stream>>>(xb, wqb, wkb, wvb, Qh, Kh, Vh);

  // RoPE on Qh, Kh (head-major)
  rope2_k<<<(64 * SS * 32) / 256, 256, 0, stream>>>(Qh, Kh, pos);

  // V transpose -> VT
  vtrans_k<<<dim3(SS / 64, BB * NH), 256, 0, stream>>>(Vh, VT);

  // attention -> context (token-major, aliases Vh which is now dead)
  attn2_k<<<dim3(SS / 64, BB * NH), 256, 0, stream>>>(Qh, Kh, VT, Cb);

  // output projection (fp32 out)
  gemm_bt_k<float><<<dim3(DM / 128, MTOT / 128), 256, 0, stream>>>(Cb, wob, out, MTOT, DM, DM);
}